// Round 1
// baseline (278.623 us; speedup 1.0000x reference)
//
#include <hip/hip_runtime.h>

#define BLOCK 256
#define GRID  2048
#define ITERS 16   // float4 per thread per array: (2^25/4) / (2048*256) = 16

typedef float vfloat4 __attribute__((ext_vector_type(4)));

__device__ __forceinline__ void kl_acc(float p, float q, float& acc) {
    // log2-space: acc += p*(log2 p - log2 q) + (1-p)*(log2(1-p) - log2(1-q))
    float omp = 1.0f - p;
    float omq = 1.0f - q;
    float d1  = __log2f(p)   - __log2f(q);
    float d2  = __log2f(omp) - __log2f(omq);
    acc = fmaf(p,   d1, acc);
    acc = fmaf(omp, d2, acc);
}

__device__ __forceinline__ void kl_acc4(vfloat4 pv, vfloat4 qv,
                                        float& a0, float& a1, float& a2, float& a3) {
    kl_acc(pv.x, qv.x, a0);
    kl_acc(pv.y, qv.y, a1);
    kl_acc(pv.z, qv.z, a2);
    kl_acc(pv.w, qv.w, a3);
}

__device__ __forceinline__ void block_reduce_and_atomic(float acc, float* out) {
    const float LN2 = 0.69314718055994530942f;
    #pragma unroll
    for (int off = 32; off > 0; off >>= 1)
        acc += __shfl_down(acc, off, 64);

    __shared__ float wave_sums[BLOCK / 64];
    const int lane = threadIdx.x & 63;
    const int wave = threadIdx.x >> 6;
    if (lane == 0) wave_sums[wave] = acc;
    __syncthreads();

    if (threadIdx.x == 0) {
        float s = 0.0f;
        #pragma unroll
        for (int w = 0; w < BLOCK / 64; ++w) s += wave_sums[w];
        atomicAdd(out, s * LN2);
    }
}

// Plain m13-style streaming kernel: grid-stride float4 over both inputs,
// compile-time trip count, no LDS staging, no NT, no manual waitcnt/sched
// fences. TLP (32 waves/CU) + compiler load clustering (#pragma unroll 4,
// ~8 loads in flight/wave) does the latency hiding.
__global__ __launch_bounds__(BLOCK, 8) void kl_div_stream(
        const vfloat4* __restrict__ p4,
        const vfloat4* __restrict__ q4,
        float* __restrict__ out) {
    const int    tid    = blockIdx.x * BLOCK + threadIdx.x;
    const size_t stride = (size_t)GRID * BLOCK;

    float a0 = 0.0f, a1 = 0.0f, a2 = 0.0f, a3 = 0.0f;

    #pragma unroll 4
    for (int k = 0; k < ITERS; ++k) {
        const size_t i = (size_t)k * stride + tid;
        vfloat4 pv = p4[i];
        vfloat4 qv = q4[i];
        kl_acc4(pv, qv, a0, a1, a2, a3);
    }

    float acc = (a0 + a1) + (a2 + a3);
    block_reduce_and_atomic(acc, out);
}

// Generic fallback: grid-stride, any N.
__global__ __launch_bounds__(BLOCK) void kl_div_generic(
        const float* __restrict__ p,
        const float* __restrict__ q,
        float* __restrict__ out,
        int n) {
    const int nvec = n >> 2;
    const vfloat4* __restrict__ p4 = reinterpret_cast<const vfloat4*>(p);
    const vfloat4* __restrict__ q4 = reinterpret_cast<const vfloat4*>(q);

    float acc = 0.0f;
    const int stride = gridDim.x * blockDim.x;
    for (int i = blockIdx.x * blockDim.x + threadIdx.x; i < nvec; i += stride) {
        vfloat4 pv = p4[i];
        vfloat4 qv = q4[i];
        kl_acc(pv.x, qv.x, acc);
        kl_acc(pv.y, qv.y, acc);
        kl_acc(pv.z, qv.z, acc);
        kl_acc(pv.w, qv.w, acc);
    }
    for (int i = (nvec << 2) + blockIdx.x * blockDim.x + threadIdx.x; i < n; i += stride) {
        kl_acc(p[i], q[i], acc);
    }
    block_reduce_and_atomic(acc, out);
}

extern "C" void kernel_launch(void* const* d_in, const int* in_sizes, int n_in,
                              void* d_out, int out_size, void* d_ws, size_t ws_size,
                              hipStream_t stream) {
    const float* p = (const float*)d_in[0];
    const float* q = (const float*)d_in[1];
    float* out = (float*)d_out;
    const int n = in_sizes[0];

    // d_out is re-poisoned to 0xAA before every timed launch — zero it.
    hipMemsetAsync(out, 0, sizeof(float), stream);

    if (n == GRID * BLOCK * ITERS * 4) {   // 2048 * 256 * 16 float4 * 4 = 2^25
        kl_div_stream<<<GRID, BLOCK, 0, stream>>>(
            reinterpret_cast<const vfloat4*>(p),
            reinterpret_cast<const vfloat4*>(q), out);
    } else {
        kl_div_generic<<<GRID, BLOCK, 0, stream>>>(p, q, out, n);
    }
}

// Round 2
// 265.552 us; speedup vs baseline: 1.0492x; 1.0492x over previous
//
#include <hip/hip_runtime.h>

#define BLOCK 256
#define GRID  2048
#define ITERS 16   // float4 per thread per array: (2^25/4) / (2048*256) = 16

typedef float vfloat4 __attribute__((ext_vector_type(4)));

__device__ __forceinline__ void kl_acc(float p, float q, float& acc) {
    // log2-space: acc += p*(log2 p - log2 q) + (1-p)*(log2(1-p) - log2(1-q))
    float omp = 1.0f - p;
    float omq = 1.0f - q;
    float d1  = __log2f(p)   - __log2f(q);
    float d2  = __log2f(omp) - __log2f(omq);
    acc = fmaf(p,   d1, acc);
    acc = fmaf(omp, d2, acc);
}

__device__ __forceinline__ void kl_acc4(vfloat4 pv, vfloat4 qv,
                                        float& a0, float& a1, float& a2, float& a3) {
    kl_acc(pv.x, qv.x, a0);
    kl_acc(pv.y, qv.y, a1);
    kl_acc(pv.z, qv.z, a2);
    kl_acc(pv.w, qv.w, a3);
}

__device__ __forceinline__ void block_reduce_and_atomic(float acc, float* out) {
    const float LN2 = 0.69314718055994530942f;
    #pragma unroll
    for (int off = 32; off > 0; off >>= 1)
        acc += __shfl_down(acc, off, 64);

    __shared__ float wave_sums[BLOCK / 64];
    const int lane = threadIdx.x & 63;
    const int wave = threadIdx.x >> 6;
    if (lane == 0) wave_sums[wave] = acc;
    __syncthreads();

    if (threadIdx.x == 0) {
        float s = 0.0f;
        #pragma unroll
        for (int w = 0; w < BLOCK / 64; ++w) s += wave_sums[w];
        atomicAdd(out, s * LN2);
    }
}

// Round-2 experiment: identical structure to round 1, ONE change — both
// stream loads are non-temporal. 2x128 MB exactly fills the 256 MB L3;
// cache-allocating loads thrash it (FETCH_SIZE showed 50% L3 hit at a
// blended 2.6 TB/s, below pure-HBM streaming). NT opts out of L3
// allocation so both streams run at HBM rate.
__global__ __launch_bounds__(BLOCK, 8) void kl_div_stream(
        const vfloat4* __restrict__ p4,
        const vfloat4* __restrict__ q4,
        float* __restrict__ out) {
    const int    tid    = blockIdx.x * BLOCK + threadIdx.x;
    const size_t stride = (size_t)GRID * BLOCK;

    float a0 = 0.0f, a1 = 0.0f, a2 = 0.0f, a3 = 0.0f;

    #pragma unroll 4
    for (int k = 0; k < ITERS; ++k) {
        const size_t i = (size_t)k * stride + tid;
        vfloat4 pv = __builtin_nontemporal_load(p4 + i);
        vfloat4 qv = __builtin_nontemporal_load(q4 + i);
        kl_acc4(pv, qv, a0, a1, a2, a3);
    }

    float acc = (a0 + a1) + (a2 + a3);
    block_reduce_and_atomic(acc, out);
}

// Generic fallback: grid-stride, any N.
__global__ __launch_bounds__(BLOCK) void kl_div_generic(
        const float* __restrict__ p,
        const float* __restrict__ q,
        float* __restrict__ out,
        int n) {
    const int nvec = n >> 2;
    const vfloat4* __restrict__ p4 = reinterpret_cast<const vfloat4*>(p);
    const vfloat4* __restrict__ q4 = reinterpret_cast<const vfloat4*>(q);

    float acc = 0.0f;
    const int stride = gridDim.x * blockDim.x;
    for (int i = blockIdx.x * blockDim.x + threadIdx.x; i < nvec; i += stride) {
        vfloat4 pv = p4[i];
        vfloat4 qv = q4[i];
        kl_acc(pv.x, qv.x, acc);
        kl_acc(pv.y, qv.y, acc);
        kl_acc(pv.z, qv.z, acc);
        kl_acc(pv.w, qv.w, acc);
    }
    for (int i = (nvec << 2) + blockIdx.x * blockDim.x + threadIdx.x; i < n; i += stride) {
        kl_acc(p[i], q[i], acc);
    }
    block_reduce_and_atomic(acc, out);
}

extern "C" void kernel_launch(void* const* d_in, const int* in_sizes, int n_in,
                              void* d_out, int out_size, void* d_ws, size_t ws_size,
                              hipStream_t stream) {
    const float* p = (const float*)d_in[0];
    const float* q = (const float*)d_in[1];
    float* out = (float*)d_out;
    const int n = in_sizes[0];

    // d_out is re-poisoned to 0xAA before every timed launch — zero it.
    hipMemsetAsync(out, 0, sizeof(float), stream);

    if (n == GRID * BLOCK * ITERS * 4) {   // 2048 * 256 * 16 float4 * 4 = 2^25
        kl_div_stream<<<GRID, BLOCK, 0, stream>>>(
            reinterpret_cast<const vfloat4*>(p),
            reinterpret_cast<const vfloat4*>(q), out);
    } else {
        kl_div_generic<<<GRID, BLOCK, 0, stream>>>(p, q, out, n);
    }
}